// Round 1
// baseline (1805.158 us; speedup 1.0000x reference)
//
#include <hip/hip_runtime.h>
#include <hip/hip_bf16.h>

#define BB 4
#define SS 1024
#define DD 1024
#define HH 16
#define HDIM 64
#define NPOSN 64
#define QB 8

// C[M,N] = A[M,K] @ W[N,K]^T + bias ; M=4096, N=K=1024
__global__ __launch_bounds__(256)
void gemm_nt_bias(const float* __restrict__ A, const float* __restrict__ W,
                  const float* __restrict__ bias, float* __restrict__ C, int M) {
  const int N = DD, K = DD;
  __shared__ float Al[16][68];
  __shared__ float Bl[16][68];
  const int tid = threadIdx.x;
  const int nbm = M >> 6;
  const int bm = blockIdx.x % nbm;
  const int bn = blockIdx.x / nbm;
  const int m0 = bm << 6, n0 = bn << 6;
  const int tm = (tid & 15) << 2;
  const int tn = (tid >> 4) << 2;
  const int lr = tid >> 2;
  const int lc = (tid & 3) << 2;
  const float* Ap = A + (size_t)(m0 + lr) * K + lc;
  const float* Wp = W + (size_t)(n0 + lr) * K + lc;
  float acc[4][4] = {};
  for (int k0 = 0; k0 < K; k0 += 16) {
    const float4 a4 = *(const float4*)(Ap + k0);
    const float4 b4 = *(const float4*)(Wp + k0);
    __syncthreads();
    Al[lc + 0][lr] = a4.x; Al[lc + 1][lr] = a4.y;
    Al[lc + 2][lr] = a4.z; Al[lc + 3][lr] = a4.w;
    Bl[lc + 0][lr] = b4.x; Bl[lc + 1][lr] = b4.y;
    Bl[lc + 2][lr] = b4.z; Bl[lc + 3][lr] = b4.w;
    __syncthreads();
#pragma unroll
    for (int k = 0; k < 16; ++k) {
      const float4 av = *(const float4*)&Al[k][tm];
      const float4 bv = *(const float4*)&Bl[k][tn];
      acc[0][0] += av.x * bv.x; acc[0][1] += av.x * bv.y;
      acc[0][2] += av.x * bv.z; acc[0][3] += av.x * bv.w;
      acc[1][0] += av.y * bv.x; acc[1][1] += av.y * bv.y;
      acc[1][2] += av.y * bv.z; acc[1][3] += av.y * bv.w;
      acc[2][0] += av.z * bv.x; acc[2][1] += av.z * bv.y;
      acc[2][2] += av.z * bv.z; acc[2][3] += av.z * bv.w;
      acc[3][0] += av.w * bv.x; acc[3][1] += av.w * bv.y;
      acc[3][2] += av.w * bv.z; acc[3][3] += av.w * bv.w;
    }
  }
  const float b0 = bias[n0 + tn + 0], b1 = bias[n0 + tn + 1];
  const float b2 = bias[n0 + tn + 2], b3 = bias[n0 + tn + 3];
#pragma unroll
  for (int i = 0; i < 4; ++i) {
    float4 o;
    o.x = acc[i][0] + b0; o.y = acc[i][1] + b1;
    o.z = acc[i][2] + b2; o.w = acc[i][3] + b3;
    *(float4*)&C[(size_t)(m0 + tm + i) * N + n0 + tn] = o;
  }
}

// One block per (b, h, 8-query tile). 256 threads = 4 waves.
__global__ __launch_bounds__(256)
void cope_attn(const float* __restrict__ Qb, const float* __restrict__ Kb,
               const float* __restrict__ Vb, const float* __restrict__ pe,
               float* __restrict__ Ob) {
  __shared__ float logl[QB][SS];     // 32 KB: full logits rows, then probs
  __shared__ float kv[64][68];       // pos_emb, then K-tile (transposed), then V-tile
  __shared__ float qs[QB][68];       // Q tile
  __shared__ float li[QB][NPOSN];    // logits_int = Q . pos_emb
  const int tid = threadIdx.x;
  const int bh = blockIdx.x >> 7;
  const int qt = blockIdx.x & 127;
  const int b = bh >> 4, h = bh & 15;
  const int q0 = qt << 3;
  const float* Qh = Qb + (size_t)b * SS * DD + h * HDIM;
  const float* Kh = Kb + (size_t)b * SS * DD + h * HDIM;
  const float* Vh = Vb + (size_t)b * SS * DD + h * HDIM;

  // Q tile [8][64]
  if (tid < 128) {
    const int r = tid >> 4, c = (tid & 15) << 2;
    *(float4*)&qs[r][c] = *(const float4*)(Qh + (size_t)(q0 + r) * DD + c);
  }
  // stage pos_emb [d][n] (row-major 64x64)
#pragma unroll
  for (int i = 0; i < 4; ++i) {
    const int f = tid + (i << 8);
    const int r = f >> 4, c = (f & 15) << 2;
    *(float4*)&kv[r][c] = *(const float4*)(pe + r * NPOSN + c);
  }
  __syncthreads();
  // logits_int[q][n] = sum_d Q[q][d] * pe[d][n]
  {
    const int n = tid & 63, qsel = tid >> 6;
    float a0 = 0.f, a1 = 0.f;
    for (int d = 0; d < HDIM; ++d) {
      const float p = kv[d][n];
      a0 += qs[qsel][d] * p;
      a1 += qs[qsel + 4][d] * p;
    }
    li[qsel][n] = a0;
    li[qsel + 4][n] = a1;
  }
  // QK^T * scale -> logl
  {
    const int k = tid & 63, qsel = tid >> 6;
    for (int kt = 0; kt < 16; ++kt) {
      __syncthreads();
#pragma unroll
      for (int i = 0; i < 4; ++i) {
        const int f = tid + (i << 8);
        const int r = f >> 4, c = (f & 15) << 2;
        const float4 v = *(const float4*)(Kh + (size_t)(kt * 64 + r) * DD + c);
        kv[c + 0][r] = v.x; kv[c + 1][r] = v.y;
        kv[c + 2][r] = v.z; kv[c + 3][r] = v.w;
      }
      __syncthreads();
      float a0 = 0.f, a1 = 0.f;
#pragma unroll
      for (int d4 = 0; d4 < HDIM; d4 += 4) {
        const float4 u0 = *(const float4*)&qs[qsel][d4];
        const float4 u1 = *(const float4*)&qs[qsel + 4][d4];
        const float k0v = kv[d4][k], k1v = kv[d4 + 1][k];
        const float k2v = kv[d4 + 2][k], k3v = kv[d4 + 3][k];
        a0 += u0.x * k0v + u0.y * k1v + u0.z * k2v + u0.w * k3v;
        a1 += u1.x * k0v + u1.y * k1v + u1.z * k2v + u1.w * k3v;
      }
      logl[qsel][(kt << 6) + k] = a0 * 0.125f;
      logl[qsel + 4][(kt << 6) + k] = a1 * 0.125f;
    }
  }
  __syncthreads();
  // CoPE gates -> reverse cumsum -> interpolated gather -> softmax.
  // Wave w handles rows 2w, 2w+1. Lane owns 16 contiguous columns.
  {
    const int lane = tid & 63;
    const int w = tid >> 6;
#pragma unroll
    for (int rr = 0; rr < 2; ++rr) {
      const int row = w * 2 + rr;
      float x[16];
      float4* rowp = (float4*)&logl[row][lane << 4];
#pragma unroll
      for (int i = 0; i < 4; ++i) {
        const float4 v = rowp[i];
        x[i * 4 + 0] = v.x; x[i * 4 + 1] = v.y;
        x[i * 4 + 2] = v.z; x[i * 4 + 3] = v.w;
      }
      // sigmoid + per-lane forward exclusive prefix
      float pref[16];
      float s = 0.f;
#pragma unroll
      for (int i = 0; i < 16; ++i) {
        const float g = 1.f / (1.f + __expf(-x[i]));
        pref[i] = s;
        s += g;
      }
      // wave inclusive scan of chunk sums
      float run = s;
#pragma unroll
      for (int off = 1; off < 64; off <<= 1) {
        const float t = __shfl_up(run, off);
        if (lane >= off) run += t;
      }
      const float T = __shfl(run, 63);
      const float excl = run - s;
      // pos[k] = suffix-sum = T - exclusive-prefix; clamp; interpolate
#pragma unroll
      for (int i = 0; i < 16; ++i) {
        float p = T - (excl + pref[i]);
        p = fminf(fmaxf(p, 0.f), 63.f);
        const float pf = floorf(p);
        const int ic = (int)ceilf(p);
        const int il = (int)pf;
        const float wt = p - pf;
        x[i] += li[row][ic] * wt + li[row][il] * (1.f - wt);
      }
      // softmax over the row
      float m = x[0];
#pragma unroll
      for (int i = 1; i < 16; ++i) m = fmaxf(m, x[i]);
#pragma unroll
      for (int off = 32; off > 0; off >>= 1) m = fmaxf(m, __shfl_xor(m, off));
      float sum = 0.f;
#pragma unroll
      for (int i = 0; i < 16; ++i) { x[i] = __expf(x[i] - m); sum += x[i]; }
#pragma unroll
      for (int off = 32; off > 0; off >>= 1) sum += __shfl_xor(sum, off);
      const float inv = 1.f / sum;
#pragma unroll
      for (int i = 0; i < 4; ++i) {
        float4 v;
        v.x = x[i * 4 + 0] * inv; v.y = x[i * 4 + 1] * inv;
        v.z = x[i * 4 + 2] * inv; v.w = x[i * 4 + 3] * inv;
        rowp[i] = v;
      }
    }
  }
  // PV
  {
    const int d = tid & 63, qsel = tid >> 6;
    float a0 = 0.f, a1 = 0.f;
    for (int vt = 0; vt < 16; ++vt) {
      __syncthreads();
#pragma unroll
      for (int i = 0; i < 4; ++i) {
        const int f = tid + (i << 8);
        const int r = f >> 4, c = (f & 15) << 2;
        *(float4*)&kv[r][c] = *(const float4*)(Vh + (size_t)(vt * 64 + r) * DD + c);
      }
      __syncthreads();
#pragma unroll
      for (int kk = 0; kk < 64; kk += 4) {
        const float4 p0 = *(const float4*)&logl[qsel][(vt << 6) + kk];
        const float4 p1 = *(const float4*)&logl[qsel + 4][(vt << 6) + kk];
        a0 += p0.x * kv[kk][d] + p0.y * kv[kk + 1][d]
            + p0.z * kv[kk + 2][d] + p0.w * kv[kk + 3][d];
        a1 += p1.x * kv[kk][d] + p1.y * kv[kk + 1][d]
            + p1.z * kv[kk + 2][d] + p1.w * kv[kk + 3][d];
      }
    }
    Ob[(size_t)(b * SS + q0 + qsel) * DD + h * HDIM + d] = a0;
    Ob[(size_t)(b * SS + q0 + qsel + 4) * DD + h * HDIM + d] = a1;
  }
}

extern "C" void kernel_launch(void* const* d_in, const int* in_sizes, int n_in,
                              void* d_out, int out_size, void* d_ws, size_t ws_size,
                              hipStream_t stream) {
  const float* q    = (const float*)d_in[0];
  const float* k    = (const float*)d_in[1];
  const float* v    = (const float*)d_in[2];
  const float* Wq_w = (const float*)d_in[3];
  const float* Wq_b = (const float*)d_in[4];
  const float* Wk_w = (const float*)d_in[5];
  const float* Wk_b = (const float*)d_in[6];
  const float* Wv_w = (const float*)d_in[7];
  const float* Wv_b = (const float*)d_in[8];
  const float* Wo_w = (const float*)d_in[9];
  const float* Wo_b = (const float*)d_in[10];
  const float* pe   = (const float*)d_in[11];
  float* out = (float*)d_out;

  const size_t NELT = (size_t)BB * SS * DD;  // 4M floats
  float* ws = (float*)d_ws;
  float* Qb = ws;
  float* Kb = ws + NELT;
  float* Vb = ws + 2 * NELT;
  float* Ob = ws + 3 * NELT;

  const int M = BB * SS;               // 4096
  const int gemm_grid = (M / 64) * (DD / 64);  // 1024

  gemm_nt_bias<<<gemm_grid, 256, 0, stream>>>(q, Wq_w, Wq_b, Qb, M);
  gemm_nt_bias<<<gemm_grid, 256, 0, stream>>>(k, Wk_w, Wk_b, Kb, M);
  gemm_nt_bias<<<gemm_grid, 256, 0, stream>>>(v, Wv_w, Wv_b, Vb, M);

  const int attn_grid = BB * HH * (SS / QB);   // 8192
  cope_attn<<<attn_grid, 256, 0, stream>>>(Qb, Kb, Vb, pe, Ob);

  gemm_nt_bias<<<gemm_grid, 256, 0, stream>>>(Ob, Wo_w, Wo_b, out, M);
}

// Round 2
// 257.150 us; speedup vs baseline: 7.0199x; 7.0199x over previous
//
#include <hip/hip_runtime.h>
#include <hip/hip_bf16.h>

typedef __attribute__((ext_vector_type(8))) short short8;
typedef __attribute__((ext_vector_type(4))) short short4v;
typedef __attribute__((ext_vector_type(4))) float f32x4;
typedef unsigned short us;

#define MFMA16(a,b,c) __builtin_amdgcn_mfma_f32_16x16x32_bf16((a),(b),(c),0,0,0)

static __device__ __forceinline__ us bf16r(float x){
  unsigned u = __builtin_bit_cast(unsigned, x);
  u = u + 0x7fffu + ((u >> 16) & 1u);
  return (us)(u >> 16);
}
static __device__ __forceinline__ unsigned pk2(float a, float b){
  return (unsigned)bf16r(a) | ((unsigned)bf16r(b) << 16);
}

// ---------------- cast fp32 -> bf16 ----------------
__global__ __launch_bounds__(256)
void castf2b(const float* __restrict__ in, us* __restrict__ out, int n){
  const int i = (blockIdx.x * 256 + threadIdx.x) * 4;
  if (i < n){
    const float4 v = *(const float4*)(in + i);
    short4v o;
    o[0] = (short)bf16r(v.x); o[1] = (short)bf16r(v.y);
    o[2] = (short)bf16r(v.z); o[3] = (short)bf16r(v.w);
    *(short4v*)(out + i) = o;
  }
}

// ---------------- pos_emb [64d][64n] fp32 -> peT [64n][64d] bf16 ----------------
__global__ __launch_bounds__(256)
void transpose_pe(const float* __restrict__ pe, us* __restrict__ peT){
  const int t = threadIdx.x;
  const int n = t & 63, dq = t >> 6;
#pragma unroll
  for (int j = 0; j < 16; ++j){
    const int d = dq * 16 + j;
    peT[n * 64 + d] = bf16r(pe[d * 64 + n]);
  }
}

// ---------------- V bf16 [4096][1024] -> VT bf16 [b][h][64d][1024s] ----------------
__global__ __launch_bounds__(256)
void transpose_v(const us* __restrict__ Vb, us* __restrict__ VT){
  __shared__ __align__(16) us tile[64 * 72];
  const int t = threadIdx.x;
  const int stile = blockIdx.x & 15;
  const int bh = blockIdx.x >> 4;
  const int b = bh >> 4, h = bh & 15;
  const int s0 = stile << 6;
#pragma unroll
  for (int c = 0; c < 2; ++c){
    const int idx = t + (c << 8);
    const int sr = idx >> 3, cw = idx & 7;
    *(short8*)&tile[sr * 72 + cw * 8] =
        *(const short8*)(Vb + ((size_t)(b * 1024 + s0 + sr)) * 1024 + h * 64 + cw * 8);
  }
  __syncthreads();
#pragma unroll
  for (int c = 0; c < 2; ++c){
    const int idx = t + (c << 8);
    const int dr = idx >> 3, sw = idx & 7;
    short8 o;
#pragma unroll
    for (int j = 0; j < 8; ++j) o[j] = (short)tile[(sw * 8 + j) * 72 + dr];
    *(short8*)(VT + ((size_t)(bh * 64 + dr)) * 1024 + s0 + sw * 8) = o;
  }
}

// ---------------- bf16 NT GEMM: C[M=4096][1024] = A[4096][1024] @ W[1024][1024]^T + bias
// 128x128 tile, BK=64, 4 waves, XOR-swizzled LDS. blockIdx.y selects problem {0,1,2}.
template<bool OUT_BF16>
__global__ __launch_bounds__(256)
void gemm3_nt(const us* __restrict__ A0, const us* __restrict__ A1, const us* __restrict__ A2,
              const us* __restrict__ W0, const us* __restrict__ W1, const us* __restrict__ W2,
              const float* __restrict__ bp0, const float* __restrict__ bp1, const float* __restrict__ bp2,
              void* __restrict__ O0, void* __restrict__ O1, void* __restrict__ O2){
  __shared__ __align__(16) us Al[128 * 64];
  __shared__ __align__(16) us Bl[128 * 64];
  const int sel = blockIdx.y;
  const us* A      = sel == 0 ? A0 : (sel == 1 ? A1 : A2);
  const us* Wm     = sel == 0 ? W0 : (sel == 1 ? W1 : W2);
  const float* bias = sel == 0 ? bp0 : (sel == 1 ? bp1 : bp2);
  void* Ov         = sel == 0 ? O0 : (sel == 1 ? O1 : O2);
  const int tid = threadIdx.x;
  const int bm = blockIdx.x & 31, bn = blockIdx.x >> 5;
  const int m0 = bm << 7, n0 = bn << 7;
  const int w = tid >> 6, l = tid & 63;
  const int lr = l & 15, lg = l >> 4;
  const int wm = (w & 1) << 6, wn = (w >> 1) << 6;
  int srow[4], scol[4], sdst[4];
#pragma unroll
  for (int c = 0; c < 4; ++c){
    const int idx = tid + (c << 8);
    const int r = idx >> 3, cw = idx & 7;
    srow[c] = r; scol[c] = cw << 3;
    sdst[c] = r * 64 + ((cw << 3) ^ ((r & 7) << 3));
  }
  const int swz = (lr & 7) << 3;
  f32x4 acc[4][4];
#pragma unroll
  for (int i = 0; i < 4; ++i)
#pragma unroll
    for (int j = 0; j < 4; ++j) acc[i][j] = (f32x4){0.f, 0.f, 0.f, 0.f};

  short8 av[4], bv[4];
#pragma unroll
  for (int c = 0; c < 4; ++c){
    av[c] = *(const short8*)(A  + (size_t)(m0 + srow[c]) * 1024 + scol[c]);
    bv[c] = *(const short8*)(Wm + (size_t)(n0 + srow[c]) * 1024 + scol[c]);
  }
  for (int k0 = 0; k0 < 1024; k0 += 64){
    __syncthreads();
#pragma unroll
    for (int c = 0; c < 4; ++c){
      *(short8*)&Al[sdst[c]] = av[c];
      *(short8*)&Bl[sdst[c]] = bv[c];
    }
    __syncthreads();
    if (k0 < 960){
#pragma unroll
      for (int c = 0; c < 4; ++c){
        av[c] = *(const short8*)(A  + (size_t)(m0 + srow[c]) * 1024 + k0 + 64 + scol[c]);
        bv[c] = *(const short8*)(Wm + (size_t)(n0 + srow[c]) * 1024 + k0 + 64 + scol[c]);
      }
    }
#pragma unroll
    for (int ks = 0; ks < 2; ++ks){
      short8 af[4], bfv[4];
#pragma unroll
      for (int mt = 0; mt < 4; ++mt)
        af[mt] = *(const short8*)&Al[(wm + mt * 16 + lr) * 64 + (((ks << 5) + (lg << 3)) ^ swz)];
#pragma unroll
      for (int nt = 0; nt < 4; ++nt)
        bfv[nt] = *(const short8*)&Bl[(wn + nt * 16 + lr) * 64 + (((ks << 5) + (lg << 3)) ^ swz)];
#pragma unroll
      for (int mt = 0; mt < 4; ++mt)
#pragma unroll
        for (int nt = 0; nt < 4; ++nt)
          acc[mt][nt] = MFMA16(af[mt], bfv[nt], acc[mt][nt]);
    }
  }
  float bb[4];
#pragma unroll
  for (int nt = 0; nt < 4; ++nt) bb[nt] = bias[n0 + wn + nt * 16 + lr];
#pragma unroll
  for (int mt = 0; mt < 4; ++mt)
#pragma unroll
    for (int nt = 0; nt < 4; ++nt)
#pragma unroll
      for (int r = 0; r < 4; ++r){
        const size_t m = m0 + wm + mt * 16 + lg * 4 + r;
        const size_t n = n0 + wn + nt * 16 + lr;
        const float vv = acc[mt][nt][r] + bb[nt];
        if (OUT_BF16) ((us*)Ov)[m * 1024 + n] = bf16r(vv);
        else          ((float*)Ov)[m * 1024 + n] = vv;
      }
}

// ---------------- fused CoPE attention: 16 queries/block, 4 waves ----------------
__global__ __launch_bounds__(256)
void cope_attn_mfma(const us* __restrict__ Qb, const us* __restrict__ Kb,
                    const us* __restrict__ VT, const us* __restrict__ peT,
                    us* __restrict__ Ob){
  __shared__ __align__(16) char smem[16 * 1028 * 4];   // fp32 logits [16][1028]; bf16 P at +32768
  __shared__ float li[16][68];
  float* logl = (float*)smem;
  const int tid = threadIdx.x;
  const int w = tid >> 6, l = tid & 63;
  const int lr = l & 15, lg = l >> 4;
  const int qt = blockIdx.x & 63;
  const int bh = blockIdx.x >> 6;
  const int b = bh >> 4, h = bh & 15;
  const int q0 = qt << 4;
  const us* Qh = Qb + ((size_t)(b * 1024 + q0)) * 1024 + h * 64;
  const us* Kh = Kb + ((size_t)(b * 1024)) * 1024 + h * 64;
  const us* Vh = VT + ((size_t)bh) * 64 * 1024;

  const short8 aq0 = *(const short8*)(Qh + (size_t)lr * 1024 + lg * 8);
  const short8 aq1 = *(const short8*)(Qh + (size_t)lr * 1024 + 32 + lg * 8);

  // logits_int[q][n] = Q . pos_emb ; wave w owns n-tile [16w,16w+16)
  {
    f32x4 a = (f32x4){0.f, 0.f, 0.f, 0.f};
    const short8 p0 = *(const short8*)(peT + (size_t)(w * 16 + lr) * 64 + lg * 8);
    const short8 p1 = *(const short8*)(peT + (size_t)(w * 16 + lr) * 64 + 32 + lg * 8);
    a = MFMA16(aq0, p0, a);
    a = MFMA16(aq1, p1, a);
#pragma unroll
    for (int r = 0; r < 4; ++r) li[lg * 4 + r][w * 16 + lr] = a[r];
  }
  // QK^T * scale -> logl ; wave w owns keys [256w, 256w+256)
  {
    const int kbase = w << 8;
    const us* Kw = Kh + (size_t)(kbase + lr) * 1024 + lg * 8;
    short8 b0 = *(const short8*)(Kw);
    short8 b1 = *(const short8*)(Kw + 32);
    for (int t = 0; t < 16; ++t){
      short8 n0v = b0, n1v = b1;
      if (t < 15){
        const us* Kn = Kw + (size_t)((t + 1) * 16) * 1024;
        n0v = *(const short8*)(Kn);
        n1v = *(const short8*)(Kn + 32);
      }
      f32x4 a = (f32x4){0.f, 0.f, 0.f, 0.f};
      a = MFMA16(aq0, b0, a);
      a = MFMA16(aq1, b1, a);
      const int kc = kbase + t * 16 + lr;
#pragma unroll
      for (int r = 0; r < 4; ++r) logl[(lg * 4 + r) * 1028 + kc] = a[r] * 0.125f;
      b0 = n0v; b1 = n1v;
    }
  }
  __syncthreads();
  // CoPE + softmax; wave w owns rows [4w,4w+4). Lane owns k = cb*256 + l*4 + j.
  unsigned pp[4][8];
#pragma unroll
  for (int rr = 0; rr < 4; ++rr){
    const int row = w * 4 + rr;
    const float* rowp = logl + row * 1028;
    f32x4 xv[4];
#pragma unroll
    for (int cb = 0; cb < 4; ++cb) xv[cb] = *(const f32x4*)(rowp + cb * 256 + l * 4);
    float s[4], pref[4][4];
#pragma unroll
    for (int cb = 0; cb < 4; ++cb){
      float run = 0.f;
#pragma unroll
      for (int j = 0; j < 4; ++j){
        const float g = 1.f / (1.f + __expf(-xv[cb][j]));
        pref[cb][j] = run;
        run += g;
      }
      s[cb] = run;
    }
    float T[4], lex[4];
#pragma unroll
    for (int cb = 0; cb < 4; ++cb){
      float run = s[cb];
#pragma unroll
      for (int off = 1; off < 64; off <<= 1){
        const float t2 = __shfl_up(run, off);
        if (l >= off) run += t2;
      }
      T[cb] = __shfl(run, 63);
      lex[cb] = run - s[cb];
    }
    float tt = 0.f, pb[4];
#pragma unroll
    for (int cb = 3; cb >= 0; --cb){ pb[cb] = tt + T[cb] - lex[cb]; tt += T[cb]; }
    float mx = -3.4e38f;
#pragma unroll
    for (int cb = 0; cb < 4; ++cb){
#pragma unroll
      for (int j = 0; j < 4; ++j){
        float p = pb[cb] - pref[cb][j];
        p = fminf(p, 63.f);
        p = fmaxf(p, 0.f);
        const float pf = floorf(p);
        const int il = (int)pf;
        const int ic = (int)ceilf(p);
        const float wt = p - pf;
        const float xx = xv[cb][j] + li[row][ic] * wt + li[row][il] * (1.f - wt);
        xv[cb][j] = xx;
        mx = fmaxf(mx, xx);
      }
    }
#pragma unroll
    for (int off = 1; off < 64; off <<= 1) mx = fmaxf(mx, __shfl_xor(mx, off));
    float sum = 0.f;
#pragma unroll
    for (int cb = 0; cb < 4; ++cb)
#pragma unroll
      for (int j = 0; j < 4; ++j){ const float e = __expf(xv[cb][j] - mx); xv[cb][j] = e; sum += e; }
#pragma unroll
    for (int off = 1; off < 64; off <<= 1) sum += __shfl_xor(sum, off);
    const float inv = 1.f / sum;
#pragma unroll
    for (int cb = 0; cb < 4; ++cb){
      pp[rr][cb * 2 + 0] = pk2(xv[cb][0] * inv, xv[cb][1] * inv);
      pp[rr][cb * 2 + 1] = pk2(xv[cb][2] * inv, xv[cb][3] * inv);
    }
  }
  __syncthreads();           // all fp32 logit reads complete
  char* Pb = smem + 32768;   // bf16 probs, XOR-swizzled
#pragma unroll
  for (int rr = 0; rr < 4; ++rr){
    const int row = w * 4 + rr;
#pragma unroll
    for (int cb = 0; cb < 4; ++cb){
      const int off = row * 2048 + ((cb * 512 + l * 8) ^ ((row & 7) << 4));
      uint2 vv; vv.x = pp[rr][cb * 2]; vv.y = pp[rr][cb * 2 + 1];
      *(uint2*)(Pb + off) = vv;
    }
  }
  __syncthreads();
  // PV: wave w owns d-tile [16w,16w+16)
  {
    const int d0 = w * 16;
    const int pswz = (lr & 7) << 4;
    f32x4 a = (f32x4){0.f, 0.f, 0.f, 0.f};
    const us* Vw = Vh + (size_t)(d0 + lr) * 1024 + lg * 8;
    short8 vb = *(const short8*)(Vw);
    for (int ks = 0; ks < 32; ++ks){
      short8 vn = vb;
      if (ks < 31) vn = *(const short8*)(Vw + (ks + 1) * 32);
      const short8 pa = *(const short8*)(Pb + lr * 2048 + (((ks << 6) + (lg << 4)) ^ pswz));
      a = MFMA16(pa, vb, a);
      vb = vn;
    }
#pragma unroll
    for (int r = 0; r < 4; ++r)
      Ob[((size_t)(b * 1024 + q0 + lg * 4 + r)) * 1024 + h * 64 + d0 + lr] = bf16r(a[r]);
  }
}

extern "C" void kernel_launch(void* const* d_in, const int* in_sizes, int n_in,
                              void* d_out, int out_size, void* d_ws, size_t ws_size,
                              hipStream_t stream) {
  const float* q    = (const float*)d_in[0];
  const float* k    = (const float*)d_in[1];
  const float* v    = (const float*)d_in[2];
  const float* Wq_w = (const float*)d_in[3];
  const float* Wq_b = (const float*)d_in[4];
  const float* Wk_w = (const float*)d_in[5];
  const float* Wk_b = (const float*)d_in[6];
  const float* Wv_w = (const float*)d_in[7];
  const float* Wv_b = (const float*)d_in[8];
  const float* Wo_w = (const float*)d_in[9];
  const float* Wo_b = (const float*)d_in[10];
  const float* pe   = (const float*)d_in[11];
  float* out = (float*)d_out;

  char* W = (char*)d_ws;
  const size_t MB = (size_t)1 << 20;
  us* qbf  = (us*)(W);
  us* kbf  = (us*)(W + 8 * MB);
  us* vbf  = (us*)(W + 16 * MB);
  us* Wqb  = (us*)(W + 24 * MB);
  us* Wkb  = (us*)(W + 26 * MB);
  us* Wvb  = (us*)(W + 28 * MB);
  us* Wob  = (us*)(W + 30 * MB);
  us* peTb = (us*)(W + 32 * MB);
  us* Qbf  = (us*)(W + 33 * MB);
  us* Kbf  = (us*)(W + 41 * MB);
  us* Vbf  = (us*)(W + 49 * MB);
  us* VTb  = qbf;   // reuse: q cast dead after Q-GEMM
  us* Obf  = kbf;   // reuse: k cast dead after K-GEMM

  castf2b<<<4096, 256, 0, stream>>>(q, qbf, 4194304);
  castf2b<<<4096, 256, 0, stream>>>(k, kbf, 4194304);
  castf2b<<<4096, 256, 0, stream>>>(v, vbf, 4194304);
  castf2b<<<1024, 256, 0, stream>>>(Wq_w, Wqb, 1048576);
  castf2b<<<1024, 256, 0, stream>>>(Wk_w, Wkb, 1048576);
  castf2b<<<1024, 256, 0, stream>>>(Wv_w, Wvb, 1048576);
  castf2b<<<1024, 256, 0, stream>>>(Wo_w, Wob, 1048576);
  transpose_pe<<<1, 256, 0, stream>>>(pe, peTb);

  gemm3_nt<true><<<dim3(256, 3), 256, 0, stream>>>(
      qbf, kbf, vbf, Wqb, Wkb, Wvb, Wq_b, Wk_b, Wv_b, Qbf, Kbf, Vbf);
  transpose_v<<<1024, 256, 0, stream>>>(Vbf, VTb);
  cope_attn_mfma<<<4096, 256, 0, stream>>>(Qbf, Kbf, VTb, peTb, Obf);
  gemm3_nt<false><<<dim3(256, 1), 256, 0, stream>>>(
      Obf, Obf, Obf, Wob, Wob, Wob, Wo_b, Wo_b, Wo_b, out, out, out);
}

// Round 3
// 220.504 us; speedup vs baseline: 8.1865x; 1.1662x over previous
//
#include <hip/hip_runtime.h>
#include <hip/hip_bf16.h>

typedef __attribute__((ext_vector_type(8))) short short8;
typedef __attribute__((ext_vector_type(4))) float f32x4;
typedef unsigned short us;

#define MFMA16(a,b,c) __builtin_amdgcn_mfma_f32_16x16x32_bf16((a),(b),(c),0,0,0)
#define LOG2E 1.4426950408889634f

static __device__ __forceinline__ us bf16r(float x){
  unsigned u = __builtin_bit_cast(unsigned, x);
  u = u + 0x7fffu + ((u >> 16) & 1u);
  return (us)(u >> 16);
}
static __device__ __forceinline__ unsigned pk2(float a, float b){
  return (unsigned)bf16r(a) | ((unsigned)bf16r(b) << 16);
}
static __device__ __forceinline__ short8 cvt8(float4 a, float4 b){
  uint4 u; u.x = pk2(a.x, a.y); u.y = pk2(a.z, a.w);
  u.z = pk2(b.x, b.y); u.w = pk2(b.z, b.w);
  return __builtin_bit_cast(short8, u);
}
static __device__ __forceinline__ float b2f(us h){
  return __builtin_bit_cast(float, (unsigned)h << 16);
}
static __device__ __forceinline__ float exp2fast(float x){
  float r; asm("v_exp_f32 %0, %1" : "=v"(r) : "v"(x)); return r;
}
static __device__ __forceinline__ float rcpfast(float x){
  float r; asm("v_rcp_f32 %0, %1" : "=v"(r) : "v"(x)); return r;
}

// ---------------- pos_emb [64d][64n] fp32 -> peT [64n][64d] bf16, pre-scaled by log2(e) ----
__global__ __launch_bounds__(256)
void transpose_pe(const float* __restrict__ pe, us* __restrict__ peT){
  const int t = threadIdx.x;
  const int n = t & 63, dq = t >> 6;
#pragma unroll
  for (int j = 0; j < 16; ++j){
    const int d = dq * 16 + j;
    peT[n * 64 + d] = bf16r(pe[d * 64 + n] * LOG2E);
  }
}

// ---------------- V bf16 [4096][1024] -> VT bf16 [b][h][64d][1024s] ----------------
__global__ __launch_bounds__(256)
void transpose_v(const us* __restrict__ Vb, us* __restrict__ VT){
  __shared__ __align__(16) us tile[64 * 72];
  const int t = threadIdx.x;
  const int stile = blockIdx.x & 15;
  const int bh = blockIdx.x >> 4;
  const int b = bh >> 4, h = bh & 15;
  const int s0 = stile << 6;
#pragma unroll
  for (int c = 0; c < 2; ++c){
    const int idx = t + (c << 8);
    const int sr = idx >> 3, cw = idx & 7;
    *(short8*)&tile[sr * 72 + cw * 8] =
        *(const short8*)(Vb + ((size_t)(b * 1024 + s0 + sr)) * 1024 + h * 64 + cw * 8);
  }
  __syncthreads();
#pragma unroll
  for (int c = 0; c < 2; ++c){
    const int idx = t + (c << 8);
    const int dr = idx >> 3, sw = idx & 7;
    short8 o;
#pragma unroll
    for (int j = 0; j < 8; ++j) o[j] = (short)tile[(sw * 8 + j) * 72 + dr];
    *(short8*)(VT + ((size_t)(bh * 64 + dr)) * 1024 + s0 + sw * 8) = o;
  }
}

// ---------------- GEMM: C[4096][1024] = A[4096][1024] @ W[1024][1024]^T + bias
// A fp32 or bf16 (in-register cvt), W fp32 (in-register cvt). 128x128 tile, BK=64.
template<bool A_BF16, bool OUT_BF16>
__global__ __launch_bounds__(256)
void gemm3(const void* __restrict__ Av0, const void* __restrict__ Av1, const void* __restrict__ Av2,
           const float* __restrict__ W0, const float* __restrict__ W1, const float* __restrict__ W2,
           const float* __restrict__ bp0, const float* __restrict__ bp1, const float* __restrict__ bp2,
           void* __restrict__ O0, void* __restrict__ O1, void* __restrict__ O2){
  __shared__ __align__(16) us Al[128 * 64];
  __shared__ __align__(16) us Bl[128 * 64];
  const int sel = blockIdx.y;
  const void* Av   = sel == 0 ? Av0 : (sel == 1 ? Av1 : Av2);
  const float* Wm  = sel == 0 ? W0  : (sel == 1 ? W1  : W2);
  const float* bias = sel == 0 ? bp0 : (sel == 1 ? bp1 : bp2);
  void* Ov         = sel == 0 ? O0  : (sel == 1 ? O1  : O2);
  const int tid = threadIdx.x;
  const int bm = blockIdx.x & 31, bn = blockIdx.x >> 5;
  const int m0 = bm << 7, n0 = bn << 7;
  const int w = tid >> 6, l = tid & 63;
  const int lr = l & 15, lg = l >> 4;
  const int wm = (w & 1) << 6, wn = (w >> 1) << 6;
  int srow[4], scol[4], sdst[4];
#pragma unroll
  for (int c = 0; c < 4; ++c){
    const int idx = tid + (c << 8);
    const int r = idx >> 3, cw = idx & 7;
    srow[c] = r; scol[c] = cw << 3;
    sdst[c] = r * 64 + ((cw << 3) ^ ((r & 7) << 3));
  }
  const int swz = (lr & 7) << 3;
  f32x4 acc[4][4];
#pragma unroll
  for (int i = 0; i < 4; ++i)
#pragma unroll
    for (int j = 0; j < 4; ++j) acc[i][j] = (f32x4){0.f, 0.f, 0.f, 0.f};

  auto ldA = [&](int c, int k) -> short8 {
    if constexpr (A_BF16){
      return *(const short8*)((const us*)Av + (size_t)(m0 + srow[c]) * 1024 + k + scol[c]);
    } else {
      const float* p = (const float*)Av + (size_t)(m0 + srow[c]) * 1024 + k + scol[c];
      return cvt8(*(const float4*)p, *(const float4*)(p + 4));
    }
  };
  auto ldW = [&](int c, int k) -> short8 {
    const float* p = Wm + (size_t)(n0 + srow[c]) * 1024 + k + scol[c];
    return cvt8(*(const float4*)p, *(const float4*)(p + 4));
  };

  short8 av[4], bv[4];
#pragma unroll
  for (int c = 0; c < 4; ++c){ av[c] = ldA(c, 0); bv[c] = ldW(c, 0); }

  for (int k0 = 0; k0 < 1024; k0 += 64){
    __syncthreads();
#pragma unroll
    for (int c = 0; c < 4; ++c){
      *(short8*)&Al[sdst[c]] = av[c];
      *(short8*)&Bl[sdst[c]] = bv[c];
    }
    __syncthreads();
    if (k0 < 960){
#pragma unroll
      for (int c = 0; c < 4; ++c){ av[c] = ldA(c, k0 + 64); bv[c] = ldW(c, k0 + 64); }
    }
#pragma unroll
    for (int ks = 0; ks < 2; ++ks){
      short8 af[4], bfv[4];
#pragma unroll
      for (int mt = 0; mt < 4; ++mt)
        af[mt] = *(const short8*)&Al[(wm + mt * 16 + lr) * 64 + (((ks << 5) + (lg << 3)) ^ swz)];
#pragma unroll
      for (int nt = 0; nt < 4; ++nt)
        bfv[nt] = *(const short8*)&Bl[(wn + nt * 16 + lr) * 64 + (((ks << 5) + (lg << 3)) ^ swz)];
#pragma unroll
      for (int mt = 0; mt < 4; ++mt)
#pragma unroll
        for (int nt = 0; nt < 4; ++nt)
          acc[mt][nt] = MFMA16(af[mt], bfv[nt], acc[mt][nt]);
    }
  }
  float bb[4];
#pragma unroll
  for (int nt = 0; nt < 4; ++nt) bb[nt] = bias[n0 + wn + nt * 16 + lr];
#pragma unroll
  for (int mt = 0; mt < 4; ++mt)
#pragma unroll
    for (int nt = 0; nt < 4; ++nt)
#pragma unroll
      for (int r = 0; r < 4; ++r){
        const size_t m = m0 + wm + mt * 16 + lg * 4 + r;
        const size_t n = n0 + wn + nt * 16 + lr;
        const float vv = acc[mt][nt][r] + bb[nt];
        if (OUT_BF16) ((us*)Ov)[m * 1024 + n] = bf16r(vv);
        else          ((float*)Ov)[m * 1024 + n] = vv;
      }
}

// ---------------- fused CoPE attention v3: 16 queries/block, 4 waves, bf16 logits ----
// All logits pre-scaled by log2(e): sigmoid(x)=rcp(1+exp2(-y)), softmax uses exp2 directly.
__global__ __launch_bounds__(256, 4)
void cope_attn_v3(const us* __restrict__ Qb, const us* __restrict__ Kb,
                  const us* __restrict__ VT, const us* __restrict__ peT,
                  us* __restrict__ Ob){
  __shared__ __align__(16) us yl[16 * 1024];   // bf16 y-logits, then P in place (swizzled)
  __shared__ float li2[16][68];                // logits_int * log2e
  const int tid = threadIdx.x;
  const int w = tid >> 6, l = tid & 63;
  const int lr = l & 15, lg = l >> 4;
  const int qt = blockIdx.x & 63;
  const int bh = blockIdx.x >> 6;
  const int b = bh >> 4, h = bh & 15;
  const int q0 = qt << 4;
  const us* Qh = Qb + ((size_t)(b * 1024 + q0)) * 1024 + h * 64;
  const us* Kh = Kb + ((size_t)(b * 1024)) * 1024 + h * 64;
  const us* Vh = VT + ((size_t)bh) * 64 * 1024;
  const float QSC = 0.125f * LOG2E;

  const short8 aq0 = *(const short8*)(Qh + (size_t)lr * 1024 + lg * 8);
  const short8 aq1 = *(const short8*)(Qh + (size_t)lr * 1024 + 32 + lg * 8);

  // li2[q][n] = (Q . pos_emb) * log2e ; wave w owns n-tile [16w,16w+16)
  {
    f32x4 a = (f32x4){0.f, 0.f, 0.f, 0.f};
    const short8 p0 = *(const short8*)(peT + (size_t)(w * 16 + lr) * 64 + lg * 8);
    const short8 p1 = *(const short8*)(peT + (size_t)(w * 16 + lr) * 64 + 32 + lg * 8);
    a = MFMA16(aq0, p0, a);
    a = MFMA16(aq1, p1, a);
#pragma unroll
    for (int r = 0; r < 4; ++r) li2[lg * 4 + r][w * 16 + lr] = a[r];
  }
  // QK^T * 0.125 * log2e -> bf16 yl (granule-XOR swizzle); wave w owns keys [256w,256w+256)
  {
    const int kbase = w << 8;
    const us* Kw = Kh + (size_t)(kbase + lr) * 1024 + lg * 8;
    short8 b0 = *(const short8*)(Kw);
    short8 b1 = *(const short8*)(Kw + 32);
    for (int t = 0; t < 16; ++t){
      short8 n0v = b0, n1v = b1;
      if (t < 15){
        const us* Kn = Kw + (size_t)((t + 1) * 16) * 1024;
        n0v = *(const short8*)(Kn);
        n1v = *(const short8*)(Kn + 32);
      }
      f32x4 a = (f32x4){0.f, 0.f, 0.f, 0.f};
      a = MFMA16(aq0, b0, a);
      a = MFMA16(aq1, b1, a);
#pragma unroll
      for (int r = 0; r < 4; ++r){
        const int row = lg * 4 + r;
        const int kc = kbase + t * 16 + lr;
        yl[row * 1024 + (((kc >> 3) ^ (row & 7)) << 3) + (kc & 7)] = bf16r(a[r] * QSC);
      }
      b0 = n0v; b1 = n1v;
    }
  }
  __syncthreads();
  // CoPE + softmax; wave w owns rows [4w,4w+4); lane owns 16 contiguous cols [16l,16l+16).
#pragma unroll
  for (int rr = 0; rr < 4; ++rr){
    const int row = w * 4 + rr;
    const int sz = row & 7;
    const int ad0 = row * 1024 + (((2 * l) ^ sz) << 3);
    const int ad1 = row * 1024 + (((2 * l + 1) ^ sz) << 3);
    const short8 y0 = *(const short8*)&yl[ad0];
    const short8 y1 = *(const short8*)&yl[ad1];
    float x[16];
#pragma unroll
    for (int j = 0; j < 8; ++j){ x[j] = b2f((us)y0[j]); x[8 + j] = b2f((us)y1[j]); }
    // sigmoid gates + per-lane exclusive prefix
    float pref[16];
    float s = 0.f;
#pragma unroll
    for (int i = 0; i < 16; ++i){
      const float g = rcpfast(1.f + exp2fast(-x[i]));
      pref[i] = s;
      s += g;
    }
    // single wave inclusive scan of lane sums
    float run = s;
#pragma unroll
    for (int off = 1; off < 64; off <<= 1){
      const float t2 = __shfl_up(run, off);
      if (l >= off) run += t2;
    }
    const float T = __shfl(run, 63);
    const float base = T - (run - s);   // T - exclusive-lane-prefix
    float mx = -3.4e38f;
#pragma unroll
    for (int i = 0; i < 16; ++i){
      float p = base - pref[i];
      p = fminf(p, 63.f);
      p = fmaxf(p, 0.f);
      const float pf = floorf(p);
      const int il = (int)pf;
      const int ic = (int)ceilf(p);
      const float wt = p - pf;
      const float xx = x[i] + li2[row][ic] * wt + li2[row][il] * (1.f - wt);
      x[i] = xx;
      mx = fmaxf(mx, xx);
    }
#pragma unroll
    for (int off = 1; off < 64; off <<= 1) mx = fmaxf(mx, __shfl_xor(mx, off));
    float sum = 0.f;
#pragma unroll
    for (int i = 0; i < 16; ++i){ const float e = exp2fast(x[i] - mx); x[i] = e; sum += e; }
#pragma unroll
    for (int off = 1; off < 64; off <<= 1) sum += __shfl_xor(sum, off);
    const float inv = rcpfast(sum);
    uint4 ua, ub;
    ua.x = pk2(x[0] * inv,  x[1] * inv);  ua.y = pk2(x[2] * inv,  x[3] * inv);
    ua.z = pk2(x[4] * inv,  x[5] * inv);  ua.w = pk2(x[6] * inv,  x[7] * inv);
    ub.x = pk2(x[8] * inv,  x[9] * inv);  ub.y = pk2(x[10] * inv, x[11] * inv);
    ub.z = pk2(x[12] * inv, x[13] * inv); ub.w = pk2(x[14] * inv, x[15] * inv);
    *(uint4*)&yl[ad0] = ua;   // in place: lane writes exactly what it read
    *(uint4*)&yl[ad1] = ub;
  }
  __syncthreads();
  // PV: wave w owns d-tile [16w,16w+16)
  {
    const int d0 = w * 16;
    const int psw = lr & 7;
    f32x4 a = (f32x4){0.f, 0.f, 0.f, 0.f};
    const us* Vw = Vh + (size_t)(d0 + lr) * 1024 + lg * 8;
    short8 vb = *(const short8*)(Vw);
    for (int ks = 0; ks < 32; ++ks){
      short8 vn = vb;
      if (ks < 31) vn = *(const short8*)(Vw + (ks + 1) * 32);
      const short8 pa = *(const short8*)&yl[lr * 1024 + ((((ks << 2) + lg) ^ psw) << 3)];
      a = MFMA16(pa, vb, a);
      vb = vn;
    }
#pragma unroll
    for (int r = 0; r < 4; ++r)
      Ob[((size_t)(b * 1024 + q0 + lg * 4 + r)) * 1024 + h * 64 + d0 + lr] = bf16r(a[r]);
  }
}

extern "C" void kernel_launch(void* const* d_in, const int* in_sizes, int n_in,
                              void* d_out, int out_size, void* d_ws, size_t ws_size,
                              hipStream_t stream) {
  const float* q    = (const float*)d_in[0];
  const float* k    = (const float*)d_in[1];
  const float* v    = (const float*)d_in[2];
  const float* Wq_w = (const float*)d_in[3];
  const float* Wq_b = (const float*)d_in[4];
  const float* Wk_w = (const float*)d_in[5];
  const float* Wk_b = (const float*)d_in[6];
  const float* Wv_w = (const float*)d_in[7];
  const float* Wv_b = (const float*)d_in[8];
  const float* Wo_w = (const float*)d_in[9];
  const float* Wo_b = (const float*)d_in[10];
  const float* pe   = (const float*)d_in[11];
  float* out = (float*)d_out;

  char* W = (char*)d_ws;
  const size_t MB = (size_t)1 << 20;
  us* Qbf = (us*)(W);
  us* Kbf = (us*)(W + 8 * MB);
  us* Vbf = (us*)(W + 16 * MB);
  us* VTb = (us*)(W + 24 * MB);
  us* Obf = (us*)(W + 32 * MB);
  us* peT = (us*)(W + 40 * MB);

  transpose_pe<<<1, 256, 0, stream>>>(pe, peT);
  gemm3<false, true><<<dim3(256, 3), 256, 0, stream>>>(
      q, k, v, Wq_w, Wk_w, Wv_w, Wq_b, Wk_b, Wv_b, Qbf, Kbf, Vbf);
  transpose_v<<<1024, 256, 0, stream>>>(Vbf, VTb);
  cope_attn_v3<<<4096, 256, 0, stream>>>(Qbf, Kbf, VTb, peT, Obf);
  gemm3<true, false><<<dim3(256, 1), 256, 0, stream>>>(
      Obf, Obf, Obf, Wo_w, Wo_w, Wo_w, Wo_b, Wo_b, Wo_b, out, out, out);
}